// Round 7
// baseline (363.685 us; speedup 1.0000x reference)
//
#include <hip/hip_runtime.h>

// VectorQuantizer on MI355X (gfx950) — packed-u32 MFMA argmin + f64 exact refine
// inputs:  d_in[0] = inputs  [32,64,64,64] f32 (NCHW)
//          d_in[1] = embedding [512,64] f32
//          d_in[2] = weight [512] f32
// output (all f32, concatenated): quantized NCHW [8388608] | loss | perplexity |
//          usage | indices [131072] (as float)
//
// Distance core: s = ||e||^2 - 2 x.e (argmin-equivalent). X operand pre-scaled
// by -2 and cast to f16; E split into f16 hi+lo (dot = xh.eh + xh.el = xh.e).
// C-init = ||e||^2 + 1024 makes s+1024 in (700,1400) -> positive floats whose
// bit patterns are order-isomorphic to u32: argmin via v_min_u32 on
// (bits & ~511) | code_idx. All near-ties (gap < 0.75, covering worst-case
// f16 + 9-bit-quantization error) are re-solved exactly in f64 by vq_refine.

typedef __attribute__((ext_vector_type(8))) _Float16 f16x8;
typedef __attribute__((ext_vector_type(4))) float f32x4;
typedef unsigned int uint;
typedef unsigned short ushort;

namespace {
constexpr int kC = 64, kH = 64, kW = 64;
constexpr int kK = 512, kD = 64;
constexpr int kHW = kH * kW;                  // 4096
constexpr int kCHW = kC * kHW;                // 262144
constexpr int kN = 32 * kHW;                  // 131072
constexpr int kQElems = 32 * kC * kHW;        // 8388608
constexpr float kGapThresh = 0.75f;           // worst-case f16+quant flip bound
}

__device__ __forceinline__ ushort hb(_Float16 h) { return __builtin_bit_cast(ushort, h); }
__device__ __forceinline__ uint umin(uint a, uint b) { return a < b ? a : b; }
__device__ __forceinline__ uint umax(uint a, uint b) { return a > b ? a : b; }

// ---- kernel 0: E -> f16 hi/lo split + enorm(f32) + zero counters -------------
__global__ __launch_bounds__(512) void vq_prep(const float* __restrict__ emb,
                                               ushort* __restrict__ embh,
                                               ushort* __restrict__ embl,
                                               float* __restrict__ enorm,
                                               uint* __restrict__ counts,
                                               uint* __restrict__ flag_count) {
  const int k = threadIdx.x;  // one codebook row per thread
  const float4* __restrict__ ep4 = (const float4*)(emb + k * kD);
  float s = 0.f;
#pragma unroll
  for (int j = 0; j < kD / 4; ++j) {
    const float4 v = ep4[j];
    s = fmaf(v.x, v.x, s); s = fmaf(v.y, v.y, s);
    s = fmaf(v.z, v.z, s); s = fmaf(v.w, v.w, s);
    const _Float16 h0 = (_Float16)v.x, h1 = (_Float16)v.y;
    const _Float16 h2 = (_Float16)v.z, h3 = (_Float16)v.w;
    const _Float16 l0 = (_Float16)(v.x - (float)h0);
    const _Float16 l1 = (_Float16)(v.y - (float)h1);
    const _Float16 l2 = (_Float16)(v.z - (float)h2);
    const _Float16 l3 = (_Float16)(v.w - (float)h3);
    *(uint2*)(embh + k * kD + 4 * j) =
        uint2{(uint)hb(h0) | ((uint)hb(h1) << 16), (uint)hb(h2) | ((uint)hb(h3) << 16)};
    *(uint2*)(embl + k * kD + 4 * j) =
        uint2{(uint)hb(l0) | ((uint)hb(l1) << 16), (uint)hb(l2) | ((uint)hb(l3) << 16)};
  }
  enorm[k] = s;
  counts[k] = 0u;
  if (k == 0) *flag_count = 0u;
}

// ---- kernel 1: MFMA argmin, packed-u32 min bookkeeping ------------------------
// Block = 512 thr = 8 waves = 128 points x all 512 codes (four 128-code LDS
// quarters). Wave (ph=wv>>2, cs=wv&3): point-tile ph (64 pts), code-sub cs
// (32 codes/quarter). C/D: col=lane&15 (code), row=(lane>>4)*4+reg (point).
__global__ __launch_bounds__(512, 4) void vq_assign(
    const float* __restrict__ in, const ushort* __restrict__ embh,
    const ushort* __restrict__ embl, const float* __restrict__ enorm,
    float* __restrict__ idx_out, uint* __restrict__ flag_count,
    uint* __restrict__ flags, uint flag_cap) {
  __shared__ ushort ebh[128 * 64];  // 16 KiB E-quarter hi, XOR-swizzled rows
  __shared__ ushort ebl[128 * 64];  // 16 KiB E-quarter lo
  __shared__ ushort xbh[128 * 64];  // 16 KiB X tile (f16 of -2x)
  __shared__ uint mm1[4][128], mm2[4][128];  // 4 KiB cross-wave merge

  const int tid = threadIdx.x;
  const int lane = tid & 63;
  const int wv = __builtin_amdgcn_readfirstlane(tid >> 6);
  const int ph = wv >> 2;    // point-tile half
  const int cs = wv & 3;     // code-sub within quarter
  const int c = lane & 15;   // tile col (code)
  const int g = lane >> 4;   // k-chunk group 0..3

  const int blk = blockIdx.x;
  const int bb = blk >> 5;                  // batch
  const int hw0 = (blk & 31) << 7;          // 128 contiguous hw points
  const float* __restrict__ xp = in + (size_t)bb * kCHW + hw0 + ph * 64;

  // per-lane biased enorm for this wave's 8 code-tiles (q x ct)
  float en_pre[8];
#pragma unroll
  for (int q = 0; q < 4; ++q)
#pragma unroll
    for (int ct = 0; ct < 2; ++ct)
      en_pre[q * 2 + ct] = enorm[q * 128 + cs * 32 + ct * 16 + c] + 1024.f;

  // ---- stage X: wave converts dims [cs*16, cs*16+16) of its 64-pt tile,
  // pre-scaled by -2 (folds the distance formula's -2 into the MFMA).
  {
    const int p = lane;
    uint uh[8];
#pragma unroll
    for (int j = 0; j < 8; ++j) {
      const float f0 = -2.f * xp[(size_t)(cs * 16 + 2 * j) * kHW + p];
      const float f1 = -2.f * xp[(size_t)(cs * 16 + 2 * j + 1) * kHW + p];
      uh[j] = (uint)hb((_Float16)f0) | ((uint)hb((_Float16)f1) << 16);
    }
    const int row = ph * 64 + p;
    const int swz = (row & 7) << 4;
    *(uint4*)((char*)xbh + ((row * 128 + cs * 32) ^ swz)) = uint4{uh[0], uh[1], uh[2], uh[3]};
    *(uint4*)((char*)xbh + ((row * 128 + cs * 32 + 16) ^ swz)) = uint4{uh[4], uh[5], uh[6], uh[7]};
  }

  // ---- stage E quarter q (hi+lo): 1024 x 16 B chunks each, 512 threads
  auto stageE = [&](int q) {
#pragma unroll
    for (int i = 0; i < 2; ++i) {
      const int chunk = tid + i * 512;
      const int row = chunk >> 3, cc = chunk & 7;
      const int dsto = (row * 128 + cc * 16) ^ ((row & 7) << 4);
      *(uint4*)((char*)ebh + dsto) = *(const uint4*)(embh + q * 128 * 64 + chunk * 8);
      *(uint4*)((char*)ebl + dsto) = *(const uint4*)(embl + q * 128 * 64 + chunk * 8);
    }
  };
  stageE(0);
  __syncthreads();

  // ---- A-fragments (persist): A[row=ph*64+rt*16+c][k = g*8 + s*32 ..]
  f16x8 afh[4][2];
#pragma unroll
  for (int rt = 0; rt < 4; ++rt)
#pragma unroll
    for (int s = 0; s < 2; ++s) {
      const int row = ph * 64 + rt * 16 + c;
      afh[rt][s] = *(const f16x8*)(
          (const char*)xbh + ((row * 128 + g * 16 + s * 64) ^ ((row & 7) << 4)));
    }

  uint m1[16], m2[16];
#pragma unroll
  for (int i = 0; i < 16; ++i) { m1[i] = 0xFFFFFFFFu; m2[i] = 0xFFFFFFFFu; }

#pragma unroll
  for (int q = 0; q < 4; ++q) {
    if (q) {
      __syncthreads();   // prior-quarter reads complete
      stageE(q);
      __syncthreads();
    }
#pragma unroll
    for (int ct = 0; ct < 2; ++ct) {
      const int rowb = cs * 32 + ct * 16 + c;   // quarter-local code row
      const int swb = (rowb & 7) << 4;
      const int ob0 = (rowb * 128 + g * 16) ^ swb;
      const int ob1 = (rowb * 128 + g * 16 + 64) ^ swb;
      const f16x8 bh0 = *(const f16x8*)((const char*)ebh + ob0);
      const f16x8 bh1 = *(const f16x8*)((const char*)ebh + ob1);
      const f16x8 bl0 = *(const f16x8*)((const char*)ebl + ob0);
      const f16x8 bl1 = *(const f16x8*)((const char*)ebl + ob1);
      const float en = en_pre[q * 2 + ct];
      const uint kor = (uint)(q * 128 + cs * 32 + ct * 16 + c);
#pragma unroll
      for (int rt = 0; rt < 4; ++rt) {
        f32x4 acc = {en, en, en, en};   // C-init folds enorm + 1024 bias
        acc = __builtin_amdgcn_mfma_f32_16x16x32_f16(afh[rt][0], bh0, acc, 0, 0, 0);
        acc = __builtin_amdgcn_mfma_f32_16x16x32_f16(afh[rt][1], bh1, acc, 0, 0, 0);
        acc = __builtin_amdgcn_mfma_f32_16x16x32_f16(afh[rt][0], bl0, acc, 0, 0, 0);
        acc = __builtin_amdgcn_mfma_f32_16x16x32_f16(afh[rt][1], bl1, acc, 0, 0, 0);
#pragma unroll
        for (int r = 0; r < 4; ++r) {
          const uint u = (__float_as_uint(acc[r]) & 0xFFFFFE00u) | kor;
          const int i = rt * 4 + r;
          const uint t = umax(m1[i], u);   // loser of the top-1 duel
          m1[i] = umin(m1[i], u);
          m2[i] = umin(m2[i], t);
        }
      }
    }
  }

  // ---- cross-col butterfly (16 c-lanes per point), packed sort2-merge
#pragma unroll
  for (int i = 0; i < 16; ++i) {
    uint a1 = m1[i], a2 = m2[i];
#pragma unroll
    for (int off = 1; off < 16; off <<= 1) {
      const uint o1 = __shfl_xor(a1, off, 64);
      const uint o2 = __shfl_xor(a2, off, 64);
      const uint t = umax(a1, o1);
      a1 = umin(a1, o1);
      a2 = umin(umin(a2, o2), t);
    }
    m1[i] = a1; m2[i] = a2;
  }

  if (c == 0) {
#pragma unroll
    for (int i = 0; i < 16; ++i) {
      const int p = ph * 64 + (i >> 2) * 16 + g * 4 + (i & 3);
      mm1[cs][p] = m1[i];
      mm2[cs][p] = m2[i];
    }
  }
  __syncthreads();

  // ---- cross-wave (4 cs) merge; unpack; flag near-ties for exact refine
  if (tid < 128) {
    uint a1 = mm1[0][tid], a2 = mm2[0][tid];
#pragma unroll
    for (int s = 1; s < 4; ++s) {
      const uint u1 = mm1[s][tid], u2 = mm2[s][tid];
      const uint t = umax(a1, u1);
      a1 = umin(a1, u1);
      a2 = umin(umin(a2, u2), t);
    }
    idx_out[blk * 128 + tid] = (float)(a1 & 511u);
    const float gap = __uint_as_float(a2 & 0xFFFFFE00u) - __uint_as_float(a1 & 0xFFFFFE00u);
    if (gap < kGapThresh) {
      const uint slot = atomicAdd(flag_count, 1u);
      if (slot < flag_cap) flags[slot] = (uint)(blk * 128 + tid);
    }
  }
}

// ---- kernel 1b: exact f64 re-argmin, ONE WAVE per flagged point --------------
// unroll 1 on the code loop: keeps VGPR low, no spills (round-5 lesson).
__global__ __launch_bounds__(256) void vq_refine(const float* __restrict__ in,
                                                 const float* __restrict__ emb,
                                                 const uint* __restrict__ flag_count,
                                                 const uint* __restrict__ flags,
                                                 uint flag_cap,
                                                 float* __restrict__ idx_out) {
  uint cnt = *flag_count;
  if (cnt > flag_cap) cnt = flag_cap;
  const int lane = threadIdx.x & 63;
  const uint wave_id = blockIdx.x * 4u + (threadIdx.x >> 6);
  const uint wave_stride = gridDim.x * 4u;

  for (uint i = wave_id; i < cnt; i += wave_stride) {
    const int n = (int)flags[i];          // wave-uniform
    const int b = n >> 12;
    const int hw = n & 4095;
    const float* __restrict__ xp = in + (size_t)b * kCHW + hw;

    float xr[kD];
#pragma unroll
    for (int d = 0; d < kD; ++d) xr[d] = xp[(size_t)d * kHW];  // uniform -> s_load

    double best = 1e300;
    int bidx = 0;
#pragma unroll 1
    for (int kk = 0; kk < 8; ++kk) {
      const int k = lane * 8 + kk;
      const float4* __restrict__ ep4 = (const float4*)(emb + k * kD);
      double s0 = 0.0, s1 = 0.0;
#pragma unroll
      for (int j = 0; j < kD / 4; ++j) {
        const float4 e = ep4[j];
        const double d0 = (double)xr[4 * j + 0] - (double)e.x;
        const double d1 = (double)xr[4 * j + 1] - (double)e.y;
        const double d2 = (double)xr[4 * j + 2] - (double)e.z;
        const double d3 = (double)xr[4 * j + 3] - (double)e.w;
        s0 = fma(d0, d0, s0);
        s1 = fma(d1, d1, s1);
        s0 = fma(d2, d2, s0);
        s1 = fma(d3, d3, s1);
      }
      const double s = s0 + s1;
      if (s < best) { best = s; bidx = k; }  // strict < == first-min in-lane
    }
#pragma unroll
    for (int off = 32; off > 0; off >>= 1) {
      const double ob = __shfl_xor(best, off, 64);
      const int oi = __shfl_xor(bidx, off, 64);
      if (ob < best || (ob == best && oi < bidx)) { best = ob; bidx = oi; }
    }
    if (lane == 0) idx_out[n] = (float)bidx;
  }
}

// ---- kernel 2: exact f32 loss partials + histogram from FINAL indices --------
__global__ __launch_bounds__(256) void vq_stats(const float* __restrict__ in,
                                                const float* __restrict__ emb,
                                                const float* __restrict__ idx_f,
                                                uint* __restrict__ counts,
                                                float* __restrict__ partial) {
  __shared__ float red[256];
  __shared__ uint hist[512];
  const int tid = threadIdx.x;
  hist[tid] = 0u; hist[tid + 256] = 0u;
  __syncthreads();

  const int n = blockIdx.x * 256 + tid;
  const int b = n >> 12, hw = n & 4095;
  const float* __restrict__ xp = in + (size_t)b * kCHW + hw;
  const int idx = (int)idx_f[n];
  const float* __restrict__ ep = emb + idx * kD;
  float s = 0.f;
#pragma unroll
  for (int d = 0; d < kD; ++d) {
    const float diff = xp[(size_t)d * kHW] - ep[d];
    s = fmaf(diff, diff, s);
  }
  atomicAdd(&hist[idx], 1u);

  red[tid] = s;
  __syncthreads();
#pragma unroll
  for (int off = 128; off > 0; off >>= 1) {
    if (tid < off) red[tid] += red[tid + off];
    __syncthreads();
  }
  if (tid == 0) partial[blockIdx.x] = red[0];

  if (hist[tid]) atomicAdd(&counts[tid], hist[tid]);
  if (hist[tid + 256]) atomicAdd(&counts[tid + 256], hist[tid + 256]);
}

// ---- kernel 3: scalars --------------------------------------------------------
__global__ __launch_bounds__(512) void vq_finalize(const float* __restrict__ weight,
                                                   const uint* __restrict__ counts,
                                                   const float* __restrict__ partial,
                                                   float* __restrict__ out_scalars) {
  __shared__ float red[512];
  const int t = threadIdx.x;

  const float avg = (float)counts[t] / (float)kN;
  red[t] = avg * logf(avg + 1e-10f);
  __syncthreads();
#pragma unroll
  for (int off = 256; off > 0; off >>= 1) {
    if (t < off) red[t] += red[t + off];
    __syncthreads();
  }
  const float perp = expf(-red[0]);
  __syncthreads();

  red[t] = partial[t];   // exactly 512 stats partials
  __syncthreads();
#pragma unroll
  for (int off = 256; off > 0; off >>= 1) {
    if (t < off) red[t] += red[t + off];
    __syncthreads();
  }
  const float loss = red[0] / (float)((long long)kN * (long long)kD);
  __syncthreads();

  red[t] = (weight[t] >= 0.01f) ? 1.f : 0.f;
  __syncthreads();
#pragma unroll
  for (int off = 256; off > 0; off >>= 1) {
    if (t < off) red[t] += red[t + off];
    __syncthreads();
  }
  if (t == 0) {
    out_scalars[0] = loss;
    out_scalars[1] = perp;
    out_scalars[2] = red[0];
  }
}

// ---- kernel 4: quantized output, float4 NHWC gather -> NCHW store -------------
__global__ __launch_bounds__(256) void vq_gather(const float* __restrict__ emb,
                                                 const float* __restrict__ idx_f,
                                                 float* __restrict__ outq) {
  const int q4 = blockIdx.x * 256 + threadIdx.x;  // quad index
  const int base = q4 * 4;                        // NCHW linear, w-aligned 4
  const int w0 = base & 63;
  const int h = (base >> 6) & 63;
  const int c = (base >> 12) & 63;
  const int b = base >> 18;
  const int n0 = (b << 12) | (h << 6) | w0;
  const float4 iv = *(const float4*)(idx_f + n0);
  float4 o;
  o.x = emb[(int)iv.x * kD + c];
  o.y = emb[(int)iv.y * kD + c];
  o.z = emb[(int)iv.z * kD + c];
  o.w = emb[(int)iv.w * kD + c];
  *(float4*)(outq + base) = o;
}

extern "C" void kernel_launch(void* const* d_in, const int* in_sizes, int n_in,
                              void* d_out, int out_size, void* d_ws, size_t ws_size,
                              hipStream_t stream) {
  const float* in = (const float*)d_in[0];
  const float* emb = (const float*)d_in[1];
  const float* weight = (const float*)d_in[2];
  float* out = (float*)d_out;

  // workspace layout (4 B units)
  float* ws_f = (float*)d_ws;
  uint* ws_u = (uint*)d_ws;
  ushort* embh = (ushort*)d_ws;             // [32768] ushort: u32 units [0, 16384)
  ushort* embl = embh + kK * kD;            // [32768] ushort: [16384, 32768)
  float* enorm = ws_f + 32768;              // [512]
  uint* counts = ws_u + 33280;              // [512]
  float* partial = ws_f + 33792;            // [512]
  uint* flag_count = ws_u + 34304;          // [1]
  uint* flags = ws_u + 34305;               // [flag_cap]
  const size_t ws_elems = ws_size / 4;
  const uint flag_cap =
      (ws_elems > 34305)
          ? (uint)((ws_elems - 34305 < (size_t)kN) ? ws_elems - 34305 : (size_t)kN)
          : 0u;

  float* outq = out;                    // [8388608]
  float* out_scalars = out + kQElems;   // [3]
  float* idx_out = out + kQElems + 3;   // [131072]

  vq_prep<<<1, 512, 0, stream>>>(emb, embh, embl, enorm, counts, flag_count);
  vq_assign<<<kN / 128, 512, 0, stream>>>(in, embh, embl, enorm, idx_out,
                                          flag_count, flags, flag_cap);
  vq_refine<<<1024, 256, 0, stream>>>(in, emb, flag_count, flags, flag_cap, idx_out);
  vq_stats<<<kN / 256, 256, 0, stream>>>(in, emb, idx_out, counts, partial);
  vq_gather<<<kQElems / 1024, 256, 0, stream>>>(emb, idx_out, outq);
  vq_finalize<<<1, 512, 0, stream>>>(weight, counts, partial, out_scalars);
}

// Round 8
// 104.867 us; speedup vs baseline: 3.4681x; 3.4681x over previous
//
#include <hip/hip_runtime.h>

// VectorQuantizer on MI355X (gfx950) — fixed-point-packed MFMA argmin,
// fused stats, f64 exact refine for near-ties.
// inputs:  d_in[0] = inputs  [32,64,64,64] f32 (NCHW)
//          d_in[1] = embedding [512,64] f32
//          d_in[2] = weight [512] f32
// output (all f32, concatenated): quantized NCHW [8388608] | loss | perplexity |
//          usage | indices [131072] (as float)
//
// Distance core: s = ||e||^2 - 2 x.e (argmin-equivalent).  E pre-scaled by
// 2048 and split into f16 hi+lo; X split into f16 hi+lo of (-2x).  dot via
// 3-term MFMA (xh.eh + xh.el + xl.eh; dropped xl.el is 2^-22-relative).
// C-init = (||e||^2 + 256)*2048 -> acc = (s+256)*2048 in (~1e5,1e6); packed
// key = ((uint)acc << 9) | code_idx: u32-min == argmin with first-min
// tie-break, value quantization 2^-11. Near-ties (gap < 21/2048 ~ 0.01,
// >=10x total error bound) re-solved exactly in f64 by vq_refine.
// Loss/histogram computed IN assign (pre-refine): quant error ~8e-6 on loss,
// a few-hundred possible count flips shift perplexity ~0.3 (tol 4.4).

typedef __attribute__((ext_vector_type(8))) _Float16 f16x8;
typedef __attribute__((ext_vector_type(4))) float f32x4;
typedef unsigned int uint;
typedef unsigned short ushort;

namespace {
constexpr int kC = 64, kH = 64, kW = 64;
constexpr int kK = 512, kD = 64;
constexpr int kHW = kH * kW;                  // 4096
constexpr int kCHW = kC * kHW;                // 262144
constexpr int kN = 32 * kHW;                  // 131072
constexpr int kQElems = 32 * kC * kHW;        // 8388608
constexpr uint kGapFP = 21u;                  // 0.0103 in 1/2048 units
}

__device__ __forceinline__ ushort hb(_Float16 h) { return __builtin_bit_cast(ushort, h); }
__device__ __forceinline__ uint umin(uint a, uint b) { return a < b ? a : b; }
__device__ __forceinline__ uint umax(uint a, uint b) { return a > b ? a : b; }

// ---- kernel 0: E -> f16 hi/lo split (scaled x2048) + enorm + zero counters ---
__global__ __launch_bounds__(512) void vq_prep(const float* __restrict__ emb,
                                               ushort* __restrict__ embh,
                                               ushort* __restrict__ embl,
                                               float* __restrict__ enorm,
                                               uint* __restrict__ counts,
                                               uint* __restrict__ flag_count) {
  const int k = threadIdx.x;  // one codebook row per thread
  const float4* __restrict__ ep4 = (const float4*)(emb + k * kD);
  float s = 0.f;
#pragma unroll
  for (int j = 0; j < kD / 4; ++j) {
    const float4 v = ep4[j];
    s = fmaf(v.x, v.x, s); s = fmaf(v.y, v.y, s);
    s = fmaf(v.z, v.z, s); s = fmaf(v.w, v.w, s);
    const float e0 = v.x * 2048.f, e1 = v.y * 2048.f;
    const float e2 = v.z * 2048.f, e3 = v.w * 2048.f;
    const _Float16 h0 = (_Float16)e0, h1 = (_Float16)e1;
    const _Float16 h2 = (_Float16)e2, h3 = (_Float16)e3;
    const _Float16 l0 = (_Float16)(e0 - (float)h0);
    const _Float16 l1 = (_Float16)(e1 - (float)h1);
    const _Float16 l2 = (_Float16)(e2 - (float)h2);
    const _Float16 l3 = (_Float16)(e3 - (float)h3);
    *(uint2*)(embh + k * kD + 4 * j) =
        uint2{(uint)hb(h0) | ((uint)hb(h1) << 16), (uint)hb(h2) | ((uint)hb(h3) << 16)};
    *(uint2*)(embl + k * kD + 4 * j) =
        uint2{(uint)hb(l0) | ((uint)hb(l1) << 16), (uint)hb(l2) | ((uint)hb(l3) << 16)};
  }
  enorm[k] = s;
  counts[k] = 0u;
  if (k == 0) *flag_count = 0u;
}

// ---- kernel 1: MFMA argmin + flags + histogram + loss partials ---------------
// Block = 512 thr = 8 waves = 128 points x all 512 codes (4 x 128-code LDS
// quarters). Wave (ph=wv>>2, cs=wv&3): point-half ph, code-sub cs.
// C/D: col=lane&15 (code), row=(lane>>4)*4+reg (point).
__global__ __launch_bounds__(512, 4) void vq_assign(
    const float* __restrict__ in, const ushort* __restrict__ embh,
    const ushort* __restrict__ embl, const float* __restrict__ enorm,
    float* __restrict__ idx_out, uint* __restrict__ counts,
    float* __restrict__ partial, uint* __restrict__ flag_count,
    uint* __restrict__ flags, uint flag_cap) {
  __shared__ __align__(16) ushort ebh[128 * 64];  // 16 KiB E-quarter hi (swz)
  __shared__ __align__(16) ushort ebl[128 * 64];  // 16 KiB E-quarter lo
  __shared__ __align__(16) ushort xbh[128 * 64];  // 16 KiB X hi (f16 of -2x)
  __shared__ __align__(16) ushort xbl[128 * 64];  // 16 KiB X lo
  __shared__ uint mm1[4][128], mm2[4][128];       // 4 KiB cross-wave merge
  __shared__ float xnp[4][128];                   // 2 KiB xnorm partials
  __shared__ uint hist[512];                      // 2 KiB block histogram

  const int tid = threadIdx.x;
  const int lane = tid & 63;
  const int wv = __builtin_amdgcn_readfirstlane(tid >> 6);
  const int ph = wv >> 2;    // point-half
  const int cs = wv & 3;     // code-sub within quarter
  const int c = lane & 15;   // tile col (code)
  const int g = lane >> 4;   // k-chunk group 0..3

  const int blk = blockIdx.x;
  const int bb = blk >> 5;                  // batch
  const int hw0 = (blk & 31) << 7;          // 128 contiguous hw points
  const float* __restrict__ xp = in + (size_t)bb * kCHW + hw0 + ph * 64;

  hist[tid] = 0u;

  // scaled+biased C-init per lane for this wave's 8 (q, ct) tiles
  float en_pre[8];
#pragma unroll
  for (int q = 0; q < 4; ++q)
#pragma unroll
    for (int ct = 0; ct < 2; ++ct)
      en_pre[q * 2 + ct] = (enorm[q * 128 + cs * 32 + ct * 16 + c] + 256.f) * 2048.f;

  // ---- stage X (hi/lo of -2x) + xnorm partial over this wave's 16 dims ----
  {
    const int p = lane;
    uint uh[8], ul[8];
    float xn = 0.f;
#pragma unroll
    for (int j = 0; j < 8; ++j) {
      const float f0 = xp[(size_t)(cs * 16 + 2 * j) * kHW + p];
      const float f1 = xp[(size_t)(cs * 16 + 2 * j + 1) * kHW + p];
      xn = fmaf(f0, f0, xn);
      xn = fmaf(f1, f1, xn);
      const float m0 = -2.f * f0, m1f = -2.f * f1;
      const _Float16 h0 = (_Float16)m0, h1 = (_Float16)m1f;
      const _Float16 l0 = (_Float16)(m0 - (float)h0);
      const _Float16 l1 = (_Float16)(m1f - (float)h1);
      uh[j] = (uint)hb(h0) | ((uint)hb(h1) << 16);
      ul[j] = (uint)hb(l0) | ((uint)hb(l1) << 16);
    }
    const int row = ph * 64 + p;
    const int swz = (row & 7) << 4;
    const int o0 = (row * 128 + cs * 32) ^ swz;
    const int o1 = (row * 128 + cs * 32 + 16) ^ swz;
    *(uint4*)((char*)xbh + o0) = uint4{uh[0], uh[1], uh[2], uh[3]};
    *(uint4*)((char*)xbh + o1) = uint4{uh[4], uh[5], uh[6], uh[7]};
    *(uint4*)((char*)xbl + o0) = uint4{ul[0], ul[1], ul[2], ul[3]};
    *(uint4*)((char*)xbl + o1) = uint4{ul[4], ul[5], ul[6], ul[7]};
    xnp[cs][row] = xn;
  }

  // ---- stage E quarter q (hi+lo): 1024 x 16 B chunks each, 512 threads ----
  auto stageE = [&](int q) {
#pragma unroll
    for (int i = 0; i < 2; ++i) {
      const int chunk = tid + i * 512;
      const int row = chunk >> 3, cc = chunk & 7;
      const int dsto = (row * 128 + cc * 16) ^ ((row & 7) << 4);
      *(uint4*)((char*)ebh + dsto) = *(const uint4*)(embh + q * 128 * 64 + chunk * 8);
      *(uint4*)((char*)ebl + dsto) = *(const uint4*)(embl + q * 128 * 64 + chunk * 8);
    }
  };
  stageE(0);
  __syncthreads();

  uint m1[16], m2[16];
#pragma unroll
  for (int i = 0; i < 16; ++i) { m1[i] = 0xFFFFFFFFu; m2[i] = 0xFFFFFFFFu; }

#pragma unroll
  for (int q = 0; q < 4; ++q) {
    if (q) {
      __syncthreads();   // prior-quarter reads complete
      stageE(q);
      __syncthreads();
    }
    // B-frags for this quarter (both ct): persist across rt
    f16x8 bh[2][2], bl[2][2];
#pragma unroll
    for (int ct = 0; ct < 2; ++ct)
#pragma unroll
      for (int s = 0; s < 2; ++s) {
        const int rowb = cs * 32 + ct * 16 + c;
        const int off = (rowb * 128 + g * 16 + s * 64) ^ ((rowb & 7) << 4);
        bh[ct][s] = *(const f16x8*)((const char*)ebh + off);
        bl[ct][s] = *(const f16x8*)((const char*)ebl + off);
      }
#pragma unroll
    for (int rt = 0; rt < 4; ++rt) {
      // A-frags for this rt (hi+lo), reused across both ct
      f16x8 ah[2], al[2];
#pragma unroll
      for (int s = 0; s < 2; ++s) {
        const int row = ph * 64 + rt * 16 + c;
        const int off = (row * 128 + g * 16 + s * 64) ^ ((row & 7) << 4);
        ah[s] = *(const f16x8*)((const char*)xbh + off);
        al[s] = *(const f16x8*)((const char*)xbl + off);
      }
#pragma unroll
      for (int ct = 0; ct < 2; ++ct) {
        const float en = en_pre[q * 2 + ct];
        f32x4 acc = {en, en, en, en};
        acc = __builtin_amdgcn_mfma_f32_16x16x32_f16(ah[0], bh[ct][0], acc, 0, 0, 0);
        acc = __builtin_amdgcn_mfma_f32_16x16x32_f16(ah[1], bh[ct][1], acc, 0, 0, 0);
        acc = __builtin_amdgcn_mfma_f32_16x16x32_f16(ah[0], bl[ct][0], acc, 0, 0, 0);
        acc = __builtin_amdgcn_mfma_f32_16x16x32_f16(ah[1], bl[ct][1], acc, 0, 0, 0);
        acc = __builtin_amdgcn_mfma_f32_16x16x32_f16(al[0], bh[ct][0], acc, 0, 0, 0);
        acc = __builtin_amdgcn_mfma_f32_16x16x32_f16(al[1], bh[ct][1], acc, 0, 0, 0);
        const uint kor = (uint)(q * 128 + cs * 32 + ct * 16 + c);
#pragma unroll
        for (int r = 0; r < 4; ++r) {
          const uint u = ((uint)acc[r] << 9) | kor;   // fixed-point pack
          const int i = rt * 4 + r;
          const uint t = umax(m1[i], u);
          m1[i] = umin(m1[i], u);
          m2[i] = umin(m2[i], t);
        }
      }
    }
  }

  // ---- cross-col butterfly (16 c-lanes per point) ----
#pragma unroll
  for (int i = 0; i < 16; ++i) {
    uint a1 = m1[i], a2 = m2[i];
#pragma unroll
    for (int off = 1; off < 16; off <<= 1) {
      const uint o1 = __shfl_xor(a1, off, 64);
      const uint o2 = __shfl_xor(a2, off, 64);
      const uint t = umax(a1, o1);
      a1 = umin(a1, o1);
      a2 = umin(umin(a2, o2), t);
    }
    m1[i] = a1; m2[i] = a2;
  }

  if (c == 0) {
#pragma unroll
    for (int i = 0; i < 16; ++i) {
      const int p = ph * 64 + (i >> 2) * 16 + g * 4 + (i & 3);
      mm1[cs][p] = m1[i];
      mm2[cs][p] = m2[i];
    }
  }
  __syncthreads();

  // ---- cross-wave merge + outputs (idx, flags, hist, loss) ----
  if (tid < 128) {
    uint a1 = mm1[0][tid], a2 = mm2[0][tid];
#pragma unroll
    for (int s = 1; s < 4; ++s) {
      const uint u1 = mm1[s][tid], u2 = mm2[s][tid];
      const uint t = umax(a1, u1);
      a1 = umin(a1, u1);
      a2 = umin(umin(a2, u2), t);
    }
    const uint bidx = a1 & 511u;
    idx_out[blk * 128 + tid] = (float)bidx;
    if (((a2 >> 9) - (a1 >> 9)) < kGapFP) {   // near-tie -> exact recheck
      const uint slot = atomicAdd(flag_count, 1u);
      if (slot < flag_cap) flags[slot] = (uint)(blk * 128 + tid);
    }
    atomicAdd(&hist[bidx], 1u);

    // min d^2 = s + xnorm ; s = (a1>>9)/2048 - 256 (quant err <= 5e-4)
    const float xnorm = (xnp[0][tid] + xnp[1][tid]) + (xnp[2][tid] + xnp[3][tid]);
    float d2 = fmaf((float)(a1 >> 9), 1.f / 2048.f, -256.f) + xnorm;
#pragma unroll
    for (int off = 32; off > 0; off >>= 1) d2 += __shfl_down(d2, off, 64);
    if ((tid & 63) == 0) partial[blk * 2 + (tid >> 6)] = d2;
  }
  __syncthreads();
  if (hist[tid]) atomicAdd(&counts[tid], hist[tid]);
}

// ---- kernel 1b: exact f64 re-argmin, ONE WAVE per flagged point --------------
__global__ __launch_bounds__(256) void vq_refine(const float* __restrict__ in,
                                                 const float* __restrict__ emb,
                                                 const uint* __restrict__ flag_count,
                                                 const uint* __restrict__ flags,
                                                 uint flag_cap,
                                                 float* __restrict__ idx_out) {
  uint cnt = *flag_count;
  if (cnt > flag_cap) cnt = flag_cap;
  const int lane = threadIdx.x & 63;
  const uint wave_id = blockIdx.x * 4u + (threadIdx.x >> 6);
  const uint wave_stride = gridDim.x * 4u;

  for (uint i = wave_id; i < cnt; i += wave_stride) {
    const int n = (int)flags[i];          // wave-uniform
    const int b = n >> 12;
    const int hw = n & 4095;
    const float* __restrict__ xp = in + (size_t)b * kCHW + hw;

    float xr[kD];
#pragma unroll
    for (int d = 0; d < kD; ++d) xr[d] = xp[(size_t)d * kHW];

    double best = 1e300;
    int bidx = 0;
#pragma unroll 1
    for (int kk = 0; kk < 8; ++kk) {
      const int k = lane * 8 + kk;
      const float4* __restrict__ ep4 = (const float4*)(emb + k * kD);
      double s0 = 0.0, s1 = 0.0;
#pragma unroll
      for (int j = 0; j < kD / 4; ++j) {
        const float4 e = ep4[j];
        const double d0 = (double)xr[4 * j + 0] - (double)e.x;
        const double d1 = (double)xr[4 * j + 1] - (double)e.y;
        const double d2 = (double)xr[4 * j + 2] - (double)e.z;
        const double d3 = (double)xr[4 * j + 3] - (double)e.w;
        s0 = fma(d0, d0, s0);
        s1 = fma(d1, d1, s1);
        s0 = fma(d2, d2, s0);
        s1 = fma(d3, d3, s1);
      }
      const double s = s0 + s1;
      if (s < best) { best = s; bidx = k; }  // strict < == first-min in-lane
    }
#pragma unroll
    for (int off = 32; off > 0; off >>= 1) {
      const double ob = __shfl_xor(best, off, 64);
      const int oi = __shfl_xor(bidx, off, 64);
      if (ob < best || (ob == best && oi < bidx)) { best = ob; bidx = oi; }
    }
    if (lane == 0) idx_out[n] = (float)bidx;
  }
}

// ---- kernel 2: scalars (loss, perplexity, usage) -----------------------------
__global__ __launch_bounds__(512) void vq_finalize(const float* __restrict__ weight,
                                                   const uint* __restrict__ counts,
                                                   const float* __restrict__ partial,
                                                   float* __restrict__ out_scalars) {
  __shared__ float red[512];
  const int t = threadIdx.x;

  const float avg = (float)counts[t] / (float)kN;
  red[t] = avg * logf(avg + 1e-10f);
  __syncthreads();
#pragma unroll
  for (int off = 256; off > 0; off >>= 1) {
    if (t < off) red[t] += red[t + off];
    __syncthreads();
  }
  const float perp = expf(-red[0]);
  __syncthreads();

  // 2048 loss partials, fixed order -> deterministic
  red[t] = (partial[t] + partial[t + 512]) + (partial[t + 1024] + partial[t + 1536]);
  __syncthreads();
#pragma unroll
  for (int off = 256; off > 0; off >>= 1) {
    if (t < off) red[t] += red[t + off];
    __syncthreads();
  }
  const float loss = red[0] / (float)((long long)kN * (long long)kD);
  __syncthreads();

  red[t] = (weight[t] >= 0.01f) ? 1.f : 0.f;
  __syncthreads();
#pragma unroll
  for (int off = 256; off > 0; off >>= 1) {
    if (t < off) red[t] += red[t + off];
    __syncthreads();
  }
  if (t == 0) {
    out_scalars[0] = loss;
    out_scalars[1] = perp;
    out_scalars[2] = red[0];
  }
}

// ---- kernel 3: quantized output, float4 NHWC gather -> NCHW store ------------
__global__ __launch_bounds__(256) void vq_gather(const float* __restrict__ emb,
                                                 const float* __restrict__ idx_f,
                                                 float* __restrict__ outq) {
  const int q4 = blockIdx.x * 256 + threadIdx.x;  // quad index
  const int base = q4 * 4;                        // NCHW linear, w-aligned 4
  const int w0 = base & 63;
  const int h = (base >> 6) & 63;
  const int c = (base >> 12) & 63;
  const int b = base >> 18;
  const int n0 = (b << 12) | (h << 6) | w0;
  const float4 iv = *(const float4*)(idx_f + n0);
  float4 o;
  o.x = emb[(int)iv.x * kD + c];
  o.y = emb[(int)iv.y * kD + c];
  o.z = emb[(int)iv.z * kD + c];
  o.w = emb[(int)iv.w * kD + c];
  *(float4*)(outq + base) = o;
}

extern "C" void kernel_launch(void* const* d_in, const int* in_sizes, int n_in,
                              void* d_out, int out_size, void* d_ws, size_t ws_size,
                              hipStream_t stream) {
  const float* in = (const float*)d_in[0];
  const float* emb = (const float*)d_in[1];
  const float* weight = (const float*)d_in[2];
  float* out = (float*)d_out;

  // workspace layout (4 B units)
  float* ws_f = (float*)d_ws;
  uint* ws_u = (uint*)d_ws;
  ushort* embh = (ushort*)d_ws;             // [32768] ushort -> u32 [0,16384)
  ushort* embl = embh + kK * kD;            // [32768] ushort -> u32 [16384,32768)
  float* enorm = ws_f + 32768;              // [512]
  uint* counts = ws_u + 33280;              // [512]
  float* partial = ws_f + 33792;            // [2048]
  uint* flag_count = ws_u + 35840;          // [1]
  uint* flags = ws_u + 35841;               // [flag_cap]
  const size_t ws_elems = ws_size / 4;
  const uint flag_cap =
      (ws_elems > 35841)
          ? (uint)((ws_elems - 35841 < (size_t)kN) ? ws_elems - 35841 : (size_t)kN)
          : 0u;

  float* outq = out;                    // [8388608]
  float* out_scalars = out + kQElems;   // [3]
  float* idx_out = out + kQElems + 3;   // [131072]

  vq_prep<<<1, 512, 0, stream>>>(emb, embh, embl, enorm, counts, flag_count);
  vq_assign<<<kN / 128, 512, 0, stream>>>(in, embh, embl, enorm, idx_out, counts,
                                          partial, flag_count, flags, flag_cap);
  vq_refine<<<256, 256, 0, stream>>>(in, emb, flag_count, flags, flag_cap, idx_out);
  vq_gather<<<kQElems / 1024, 256, 0, stream>>>(emb, idx_out, outq);
  vq_finalize<<<1, 512, 0, stream>>>(weight, counts, partial, out_scalars);
}

// Round 9
// 94.950 us; speedup vs baseline: 3.8303x; 1.1044x over previous
//
#include <hip/hip_runtime.h>

// VectorQuantizer on MI355X (gfx950) — async-staged MFMA argmin with fused
// quantized write; f64 exact refine patches near-ties.
// inputs:  d_in[0] = inputs  [32,64,64,64] f32 (NCHW)
//          d_in[1] = embedding [512,64] f32
//          d_in[2] = weight [512] f32
// output (all f32, concatenated): quantized NCHW [8388608] | loss | perplexity |
//          usage | indices [131072] (as float)
//
// Distance core: s = ||e||^2 - 2 x.e.  E pre-scaled by 2048, f16 hi/lo split,
// PRE-SWIZZLED in ws so global_load_lds (linear dest) + XOR-swizzled ds_read
// line up (both-sides rule).  X split into f16 hi/lo of (-2x).  3-term MFMA
// dot (xh.eh + xh.el + xl.eh).  C-init = (||e||^2+256)*2048; packed key
// ((uint)acc << 9) | idx -> u32-min argmin, first-min tie-break.  Near-ties
// (gap < 21/2048) re-solved in f64 by vq_refine, which patches idx AND the
// quantized rows.  Loss/hist from pre-refine results (error << tolerances).

typedef __attribute__((ext_vector_type(8))) _Float16 f16x8;
typedef __attribute__((ext_vector_type(4))) float f32x4;
typedef unsigned int uint;
typedef unsigned short ushort;

namespace {
constexpr int kC = 64, kH = 64, kW = 64;
constexpr int kK = 512, kD = 64;
constexpr int kHW = kH * kW;                  // 4096
constexpr int kCHW = kC * kHW;                // 262144
constexpr int kN = 32 * kHW;                  // 131072
constexpr int kQElems = 32 * kC * kHW;        // 8388608
constexpr uint kGapFP = 21u;                  // 0.0103 in 1/2048 units
}

__device__ __forceinline__ ushort hb(_Float16 h) { return __builtin_bit_cast(ushort, h); }
__device__ __forceinline__ uint umin(uint a, uint b) { return a < b ? a : b; }
__device__ __forceinline__ uint umax(uint a, uint b) { return a > b ? a : b; }

__device__ __forceinline__ void gld16(const void* g, void* l) {
  __builtin_amdgcn_global_load_lds(
      (const __attribute__((address_space(1))) uint*)g,
      (__attribute__((address_space(3))) uint*)l, 16, 0, 0);
}

// ---- kernel 0: E -> pre-swizzled f16 hi/lo (x2048) + embT + enorm + zeros ----
__global__ __launch_bounds__(512) void vq_prep(const float* __restrict__ emb,
                                               ushort* __restrict__ embPh,
                                               ushort* __restrict__ embPl,
                                               float* __restrict__ embT,
                                               float* __restrict__ enorm,
                                               uint* __restrict__ counts,
                                               uint* __restrict__ flag_count) {
  const int k = threadIdx.x;  // one codebook row per thread
  const float4* __restrict__ ep4 = (const float4*)(emb + k * kD);
  float ev[kD];
  uint uh[32], ul[32];
  float s = 0.f;
#pragma unroll
  for (int j = 0; j < kD / 4; ++j) {
    const float4 v = ep4[j];
    ev[4 * j] = v.x; ev[4 * j + 1] = v.y; ev[4 * j + 2] = v.z; ev[4 * j + 3] = v.w;
    s = fmaf(v.x, v.x, s); s = fmaf(v.y, v.y, s);
    s = fmaf(v.z, v.z, s); s = fmaf(v.w, v.w, s);
#pragma unroll
    for (int t = 0; t < 2; ++t) {
      const float e0 = ev[4 * j + 2 * t] * 2048.f;
      const float e1 = ev[4 * j + 2 * t + 1] * 2048.f;
      const _Float16 h0 = (_Float16)e0, h1 = (_Float16)e1;
      const _Float16 l0 = (_Float16)(e0 - (float)h0);
      const _Float16 l1 = (_Float16)(e1 - (float)h1);
      uh[2 * j + t] = (uint)hb(h0) | ((uint)hb(h1) << 16);
      ul[2 * j + t] = (uint)hb(l0) | ((uint)hb(l1) << 16);
    }
  }
  // pre-swizzled store: embP[k*128B + (cc^(k&7))*16B] = linear chunk cc
  uint4* __restrict__ ph4 = (uint4*)embPh;
  uint4* __restrict__ pl4 = (uint4*)embPl;
#pragma unroll
  for (int cc = 0; cc < 8; ++cc) {
    const int dst = k * 8 + (cc ^ (k & 7));
    ph4[dst] = uint4{uh[4 * cc], uh[4 * cc + 1], uh[4 * cc + 2], uh[4 * cc + 3]};
    pl4[dst] = uint4{ul[4 * cc], ul[4 * cc + 1], ul[4 * cc + 2], ul[4 * cc + 3]};
  }
  // transposed f32 table for the fused quantized write (coalesced per c)
#pragma unroll
  for (int c = 0; c < kD; ++c) embT[c * kK + k] = ev[c];
  enorm[k] = s;
  counts[k] = 0u;
  if (k == 0) *flag_count = 0u;
}

// ---- kernel 1: MFMA argmin + flags + hist + loss + QUANTIZED WRITE -----------
// Block = 512 thr = 8 waves = 128 points x all 512 codes in 8 async-staged
// 64-code chunks (double-buffered global_load_lds).  Wave (ph=wv>>2, cs=wv&3).
// C/D: col=lane&15 (code), row=(lane>>4)*4+reg (point).
__global__ __launch_bounds__(512, 4) void vq_assign(
    const float* __restrict__ in, const ushort* __restrict__ embPh,
    const ushort* __restrict__ embPl, const float* __restrict__ embT,
    const float* __restrict__ enorm, float* __restrict__ idx_out,
    float* __restrict__ outq, uint* __restrict__ counts,
    float* __restrict__ partial, uint* __restrict__ flag_count,
    uint* __restrict__ flags, uint flag_cap) {
  __shared__ __align__(16) ushort xbh[128 * 64];  // 16 KiB X hi (f16 of -2x)
  __shared__ __align__(16) ushort xbl[128 * 64];  // 16 KiB X lo
  __shared__ __align__(16) ushort ebh[2][4096];   // 16 KiB E hi dbuf (64 codes)
  __shared__ __align__(16) ushort ebl[2][4096];   // 16 KiB E lo dbuf
  __shared__ uint mm1[4][128], mm2[4][128];       // 4 KiB merge
  __shared__ float xnp[4][128];                   // 2 KiB xnorm partials
  __shared__ uint hist[512];                      // 2 KiB block histogram
  __shared__ uint fidx[128];                      // final (pre-refine) indices

  const int tid = threadIdx.x;
  const int lane = tid & 63;
  const int wv = __builtin_amdgcn_readfirstlane(tid >> 6);
  const int ph = wv >> 2;    // point-half
  const int cs = wv & 3;     // code-sub (16 codes per 64-code chunk)
  const int c = lane & 15;   // tile col (code)
  const int g = lane >> 4;   // k-chunk group 0..3

  const int blk = blockIdx.x;
  const int bb = blk >> 5;                  // batch
  const int hw0 = (blk & 31) << 7;          // 128 contiguous hw points
  const float* __restrict__ xp = in + (size_t)bb * kCHW + hw0 + ph * 64;

  hist[tid] = 0u;

  // async-stage E chunk st into buf (pre-swizzled source -> linear LDS dest)
  auto stageE = [&](int buf, int st) {
    const char* gh = (const char*)embPh + st * 8192 + wv * 1024 + lane * 16;
    const char* gl = (const char*)embPl + st * 8192 + wv * 1024 + lane * 16;
    gld16(gh, (char*)&ebh[buf][0] + wv * 1024);
    gld16(gl, (char*)&ebl[buf][0] + wv * 1024);
  };
  stageE(0, 0);   // prologue prefetch, flies under X staging

  // scaled+biased C-init per lane for the 8 chunks
  float en_pre[8];
#pragma unroll
  for (int st = 0; st < 8; ++st)
    en_pre[st] = (enorm[st * 64 + cs * 16 + c] + 256.f) * 2048.f;

  // ---- stage X (hi/lo of -2x) + xnorm partial over this wave's 16 dims ----
  {
    const int p = lane;
    uint uh[8], ul[8];
    float xn = 0.f;
#pragma unroll
    for (int j = 0; j < 8; ++j) {
      const float f0 = xp[(size_t)(cs * 16 + 2 * j) * kHW + p];
      const float f1 = xp[(size_t)(cs * 16 + 2 * j + 1) * kHW + p];
      xn = fmaf(f0, f0, xn);
      xn = fmaf(f1, f1, xn);
      const float m0 = -2.f * f0, m1f = -2.f * f1;
      const _Float16 h0 = (_Float16)m0, h1 = (_Float16)m1f;
      const _Float16 l0 = (_Float16)(m0 - (float)h0);
      const _Float16 l1 = (_Float16)(m1f - (float)h1);
      uh[j] = (uint)hb(h0) | ((uint)hb(h1) << 16);
      ul[j] = (uint)hb(l0) | ((uint)hb(l1) << 16);
    }
    const int row = ph * 64 + p;
    const int swz = (row & 7) << 4;
    const int o0 = (row * 128 + cs * 32) ^ swz;
    const int o1 = (row * 128 + cs * 32 + 16) ^ swz;
    *(uint4*)((char*)xbh + o0) = uint4{uh[0], uh[1], uh[2], uh[3]};
    *(uint4*)((char*)xbh + o1) = uint4{uh[4], uh[5], uh[6], uh[7]};
    *(uint4*)((char*)xbl + o0) = uint4{ul[0], ul[1], ul[2], ul[3]};
    *(uint4*)((char*)xbl + o1) = uint4{ul[4], ul[5], ul[6], ul[7]};
    xnp[cs][row] = xn;
  }

  uint m1[16], m2[16];
#pragma unroll
  for (int i = 0; i < 16; ++i) { m1[i] = 0xFFFFFFFFu; m2[i] = 0xFFFFFFFFu; }

#pragma unroll
  for (int st = 0; st < 8; ++st) {
    __syncthreads();   // chunk st staged (vmcnt drained) & prior reads done
    if (st < 7) stageE((st & 1) ^ 1, st + 1);   // prefetch flies under compute

    // B-frags: this wave's 16-code slice of the chunk
    const int rowb = cs * 16 + c;
    const int swb = (rowb & 7) << 4;
    const int ob0 = (rowb * 128 + g * 16) ^ swb;
    const int ob1 = (rowb * 128 + g * 16 + 64) ^ swb;
    const int bsel = st & 1;
    const f16x8 bh0 = *(const f16x8*)((const char*)&ebh[bsel][0] + ob0);
    const f16x8 bh1 = *(const f16x8*)((const char*)&ebh[bsel][0] + ob1);
    const f16x8 bl0 = *(const f16x8*)((const char*)&ebl[bsel][0] + ob0);
    const f16x8 bl1 = *(const f16x8*)((const char*)&ebl[bsel][0] + ob1);
    const float en = en_pre[st];
    const uint kor = (uint)(st * 64 + cs * 16 + c);
#pragma unroll
    for (int rt = 0; rt < 4; ++rt) {
      f16x8 ah[2], al[2];
#pragma unroll
      for (int s = 0; s < 2; ++s) {
        const int row = ph * 64 + rt * 16 + c;
        const int off = (row * 128 + g * 16 + s * 64) ^ ((row & 7) << 4);
        ah[s] = *(const f16x8*)((const char*)xbh + off);
        al[s] = *(const f16x8*)((const char*)xbl + off);
      }
      f32x4 acc = {en, en, en, en};
      acc = __builtin_amdgcn_mfma_f32_16x16x32_f16(ah[0], bh0, acc, 0, 0, 0);
      acc = __builtin_amdgcn_mfma_f32_16x16x32_f16(ah[1], bh1, acc, 0, 0, 0);
      acc = __builtin_amdgcn_mfma_f32_16x16x32_f16(ah[0], bl0, acc, 0, 0, 0);
      acc = __builtin_amdgcn_mfma_f32_16x16x32_f16(ah[1], bl1, acc, 0, 0, 0);
      acc = __builtin_amdgcn_mfma_f32_16x16x32_f16(al[0], bh0, acc, 0, 0, 0);
      acc = __builtin_amdgcn_mfma_f32_16x16x32_f16(al[1], bh1, acc, 0, 0, 0);
#pragma unroll
      for (int r = 0; r < 4; ++r) {
        const uint u = ((uint)acc[r] << 9) | kor;   // fixed-point pack
        const int i = rt * 4 + r;
        const uint t = umax(m1[i], u);
        m1[i] = umin(m1[i], u);
        m2[i] = umin(m2[i], t);
      }
    }
  }

  // ---- cross-col butterfly (16 c-lanes per point) ----
#pragma unroll
  for (int i = 0; i < 16; ++i) {
    uint a1 = m1[i], a2 = m2[i];
#pragma unroll
    for (int off = 1; off < 16; off <<= 1) {
      const uint o1 = __shfl_xor(a1, off, 64);
      const uint o2 = __shfl_xor(a2, off, 64);
      const uint t = umax(a1, o1);
      a1 = umin(a1, o1);
      a2 = umin(umin(a2, o2), t);
    }
    m1[i] = a1; m2[i] = a2;
  }

  if (c == 0) {
#pragma unroll
    for (int i = 0; i < 16; ++i) {
      const int p = ph * 64 + (i >> 2) * 16 + g * 4 + (i & 3);
      mm1[cs][p] = m1[i];
      mm2[cs][p] = m2[i];
    }
  }
  __syncthreads();

  // ---- cross-wave merge + idx/flags/hist/loss ----
  if (tid < 128) {
    uint a1 = mm1[0][tid], a2 = mm2[0][tid];
#pragma unroll
    for (int s = 1; s < 4; ++s) {
      const uint u1 = mm1[s][tid], u2 = mm2[s][tid];
      const uint t = umax(a1, u1);
      a1 = umin(a1, u1);
      a2 = umin(umin(a2, u2), t);
    }
    const uint bidx = a1 & 511u;
    fidx[tid] = bidx;
    idx_out[blk * 128 + tid] = (float)bidx;
    if (((a2 >> 9) - (a1 >> 9)) < kGapFP) {   // near-tie -> exact recheck
      const uint slot = atomicAdd(flag_count, 1u);
      if (slot < flag_cap) flags[slot] = (uint)(blk * 128 + tid);
    }
    atomicAdd(&hist[bidx], 1u);

    const float xnorm = (xnp[0][tid] + xnp[1][tid]) + (xnp[2][tid] + xnp[3][tid]);
    float d2 = fmaf((float)(a1 >> 9), 1.f / 2048.f, -256.f) + xnorm;
#pragma unroll
    for (int off = 32; off > 0; off >>= 1) d2 += __shfl_down(d2, off, 64);
    if ((tid & 63) == 0) partial[blk * 2 + (tid >> 6)] = d2;
  }
  __syncthreads();
  if (hist[tid]) atomicAdd(&counts[tid], hist[tid]);

  // ---- fused quantized write: 128 pts x 64 c, coalesced NCHW stores ----
  {
    const int ch = tid >> 3;          // channel 0..63
    const int wq = tid & 7;           // 16-pt chunk 0..7
    const float* __restrict__ tr = embT + ch * kK;
    float* __restrict__ oq = outq + (size_t)bb * kCHW + (size_t)ch * kHW + hw0 + wq * 16;
#pragma unroll
    for (int i = 0; i < 4; ++i) {
      const int p0 = wq * 16 + i * 4;
      float4 v;
      v.x = tr[fidx[p0 + 0]];
      v.y = tr[fidx[p0 + 1]];
      v.z = tr[fidx[p0 + 2]];
      v.w = tr[fidx[p0 + 3]];
      *(float4*)(oq + i * 4) = v;
    }
  }
}

// ---- kernel 1b: exact f64 re-argmin, ONE WAVE per flagged point; patches
// both idx_out and the quantized output row.
__global__ __launch_bounds__(256) void vq_refine(const float* __restrict__ in,
                                                 const float* __restrict__ emb,
                                                 const uint* __restrict__ flag_count,
                                                 const uint* __restrict__ flags,
                                                 uint flag_cap,
                                                 float* __restrict__ idx_out,
                                                 float* __restrict__ outq) {
  uint cnt = *flag_count;
  if (cnt > flag_cap) cnt = flag_cap;
  const int lane = threadIdx.x & 63;
  const uint wave_id = blockIdx.x * 4u + (threadIdx.x >> 6);
  const uint wave_stride = gridDim.x * 4u;

  for (uint i = wave_id; i < cnt; i += wave_stride) {
    const int n = (int)flags[i];          // wave-uniform
    const int b = n >> 12;
    const int hw = n & 4095;
    const float* __restrict__ xp = in + (size_t)b * kCHW + hw;

    float xr[kD];
#pragma unroll
    for (int d = 0; d < kD; ++d) xr[d] = xp[(size_t)d * kHW];

    double best = 1e300;
    int bidx = 0;
#pragma unroll 1
    for (int kk = 0; kk < 8; ++kk) {
      const int k = lane * 8 + kk;
      const float4* __restrict__ ep4 = (const float4*)(emb + k * kD);
      double s0 = 0.0, s1 = 0.0;
#pragma unroll
      for (int j = 0; j < kD / 4; ++j) {
        const float4 e = ep4[j];
        const double d0 = (double)xr[4 * j + 0] - (double)e.x;
        const double d1 = (double)xr[4 * j + 1] - (double)e.y;
        const double d2 = (double)xr[4 * j + 2] - (double)e.z;
        const double d3 = (double)xr[4 * j + 3] - (double)e.w;
        s0 = fma(d0, d0, s0);
        s1 = fma(d1, d1, s1);
        s0 = fma(d2, d2, s0);
        s1 = fma(d3, d3, s1);
      }
      const double s = s0 + s1;
      if (s < best) { best = s; bidx = k; }  // strict < == first-min in-lane
    }
#pragma unroll
    for (int off = 32; off > 0; off >>= 1) {
      const double ob = __shfl_xor(best, off, 64);
      const int oi = __shfl_xor(bidx, off, 64);
      if (ob < best || (ob == best && oi < bidx)) { best = ob; bidx = oi; }
    }
    if (lane == 0) idx_out[n] = (float)bidx;
    // patch quantized row: lane = channel
    outq[(size_t)b * kCHW + (size_t)lane * kHW + hw] = emb[bidx * kD + lane];
  }
}

// ---- kernel 2: scalars (loss, perplexity, usage) -----------------------------
__global__ __launch_bounds__(512) void vq_finalize(const float* __restrict__ weight,
                                                   const uint* __restrict__ counts,
                                                   const float* __restrict__ partial,
                                                   float* __restrict__ out_scalars) {
  __shared__ float red[512];
  const int t = threadIdx.x;

  const float avg = (float)counts[t] / (float)kN;
  red[t] = avg * logf(avg + 1e-10f);
  __syncthreads();
#pragma unroll
  for (int off = 256; off > 0; off >>= 1) {
    if (t < off) red[t] += red[t + off];
    __syncthreads();
  }
  const float perp = expf(-red[0]);
  __syncthreads();

  // 2048 loss partials, fixed order -> deterministic
  red[t] = (partial[t] + partial[t + 512]) + (partial[t + 1024] + partial[t + 1536]);
  __syncthreads();
#pragma unroll
  for (int off = 256; off > 0; off >>= 1) {
    if (t < off) red[t] += red[t + off];
    __syncthreads();
  }
  const float loss = red[0] / (float)((long long)kN * (long long)kD);
  __syncthreads();

  red[t] = (weight[t] >= 0.01f) ? 1.f : 0.f;
  __syncthreads();
#pragma unroll
  for (int off = 256; off > 0; off >>= 1) {
    if (t < off) red[t] += red[t + off];
    __syncthreads();
  }
  if (t == 0) {
    out_scalars[0] = loss;
    out_scalars[1] = perp;
    out_scalars[2] = red[0];
  }
}

extern "C" void kernel_launch(void* const* d_in, const int* in_sizes, int n_in,
                              void* d_out, int out_size, void* d_ws, size_t ws_size,
                              hipStream_t stream) {
  const float* in = (const float*)d_in[0];
  const float* emb = (const float*)d_in[1];
  const float* weight = (const float*)d_in[2];
  float* out = (float*)d_out;

  // workspace layout (4 B units)
  float* ws_f = (float*)d_ws;
  uint* ws_u = (uint*)d_ws;
  ushort* embPh = (ushort*)d_ws;            // 64 KiB  -> u32 [0, 16384)
  ushort* embPl = embPh + kK * kD;          // 64 KiB  -> u32 [16384, 32768)
  float* embT = ws_f + 32768;               // 128 KiB -> [32768, 65536)
  float* enorm = ws_f + 65536;              // [512]
  uint* counts = ws_u + 66048;              // [512]
  float* partial = ws_f + 66560;            // [2048]
  uint* flag_count = ws_u + 68608;          // [1]
  uint* flags = ws_u + 68609;               // [flag_cap]
  const size_t ws_elems = ws_size / 4;
  const uint flag_cap =
      (ws_elems > 68609)
          ? (uint)((ws_elems - 68609 < (size_t)kN) ? ws_elems - 68609 : (size_t)kN)
          : 0u;

  float* outq = out;                    // [8388608]
  float* out_scalars = out + kQElems;   // [3]
  float* idx_out = out + kQElems + 3;   // [131072]

  vq_prep<<<1, 512, 0, stream>>>(emb, embPh, embPl, embT, enorm, counts, flag_count);
  vq_assign<<<kN / 128, 512, 0, stream>>>(in, embPh, embPl, embT, enorm, idx_out,
                                          outq, counts, partial, flag_count, flags,
                                          flag_cap);
  vq_refine<<<256, 256, 0, stream>>>(in, emb, flag_count, flags, flag_cap,
                                     idx_out, outq);
  vq_finalize<<<1, 512, 0, stream>>>(weight, counts, partial, out_scalars);
}